// Round 1
// baseline (5974.646 us; speedup 1.0000x reference)
//
#include <hip/hip_runtime.h>
#include <stdint.h>

// Problem constants: B=32, T=512, I=1024, H=1024, 4H=4096, M=B*T=16384.
#define BB 32
#define TT 512
#define KK 1024
#define GG 4096
#define MM 16384
#define SCAN_WGS 128

typedef __attribute__((ext_vector_type(8))) short short8;
typedef __attribute__((ext_vector_type(4))) short short4v;
typedef __attribute__((ext_vector_type(4))) float f32x4;

__device__ inline short f2bf(float f) {
  union { float f; unsigned u; } v; v.f = f;
  unsigned r = (v.u + 0x7FFFu + ((v.u >> 16) & 1u)) >> 16;  // RNE
  return (short)(unsigned short)r;
}
__device__ inline float bf2f(short s) {
  union { unsigned u; float f; } v; v.u = ((unsigned)(unsigned short)s) << 16;
  return v.f;
}
__device__ inline float sigmoid_f(float x) { return 1.0f / (1.0f + __expf(-x)); }
__device__ inline float tanh_f(float x)    { return 1.0f - 2.0f / (__expf(2.0f * x) + 1.0f); }

// ---------------- prep kernels ----------------

__global__ void zero_ws(unsigned* __restrict__ p, int n) {
  int i = blockIdx.x * 256 + threadIdx.x;
  if (i < n) p[i] = 0u;
}

// float -> bf16, 4 elements/thread
__global__ void cvt_bf16(const float* __restrict__ in, short* __restrict__ out, int n4) {
  int i = blockIdx.x * 256 + threadIdx.x;
  if (i >= n4) return;
  f32x4 v = *(const f32x4*)(in + (size_t)i * 4);
  short4v o;
  o.x = f2bf(v.x); o.y = f2bf(v.y); o.z = f2bf(v.z); o.w = f2bf(v.w);
  *(short4v*)(out + (size_t)i * 4) = o;
}

// Pack W_hh into per-WG MFMA-B-fragment order:
// wpack[((wg*2+nt)*32 + s)*512 + lane*8 + j] = bf16(W_hh[row][k])
//   where cl = nt*16 + (lane&15); gate = cl>>3; jj = cl&7;
//   row = gate*1024 + wg*8 + jj; k = s*32 + (lane>>4)*8 + j.
__global__ void pack_whh(const float* __restrict__ Whh, short* __restrict__ wpack) {
  int idx = blockIdx.x * 256 + threadIdx.x;          // < 128*2*32*64 = 524288
  if (idx >= SCAN_WGS * 2 * 32 * 64) return;
  int lane = idx & 63;
  int s    = (idx >> 6) & 31;
  int nt   = (idx >> 11) & 1;
  int wg   = idx >> 12;
  int cl   = nt * 16 + (lane & 15);
  int gate = cl >> 3, jj = cl & 7;
  int row  = gate * 1024 + wg * 8 + jj;
  int k    = s * 32 + (lane >> 4) * 8;
  const float* src = Whh + (size_t)row * KK + k;
  short8 v;
#pragma unroll
  for (int j = 0; j < 8; ++j) v[j] = f2bf(src[j]);
  *(short8*)(wpack + ((size_t)((wg * 2 + nt) * 32 + s)) * 512 + lane * 8) = v;
}

// ---------------- phase 1: xW = x @ W_ih^T + b ----------------
// A = x bf16 [16384][1024]; B = W_ih bf16 [4096][1024] (row-major = B^T form).
// 128x128 tile, BK=32, 256 threads (4 waves in 2x2), 4x4 MFMA tiles per wave.
template <bool XWF32>
__global__ __launch_bounds__(256) void gemm_xw(const short* __restrict__ A,
                                               const short* __restrict__ Bw,
                                               const float* __restrict__ bias,
                                               void* __restrict__ Cv) {
  __shared__ short As[128 * 32];
  __shared__ short Bs[128 * 32];
  const int tid = threadIdx.x;
  const int m0 = blockIdx.y * 128;
  const int n0 = blockIdx.x * 128;
  const int lane = tid & 63, wv = tid >> 6;
  const int wm = (wv >> 1) * 64, wn = (wv & 1) * 64;
  const int fr = lane & 15;               // fragment row/col
  const int fq = (lane >> 4) * 8;         // k-offset (elements)
  const int quad = lane >> 4;
  f32x4 acc[4][4];
#pragma unroll
  for (int i = 0; i < 4; ++i)
#pragma unroll
    for (int j = 0; j < 4; ++j) acc[i][j] = (f32x4){0.f, 0.f, 0.f, 0.f};

  const int sr = tid >> 2;                // staging row 0..63
  const int sc = (tid & 3) * 8;           // staging elem offset
  const short* Ag = A + (size_t)(m0 + sr) * KK + sc;
  const short* Bg = Bw + (size_t)(n0 + sr) * KK + sc;

  for (int kb = 0; kb < KK; kb += 32) {
    short8 a0 = *(const short8*)(Ag + kb);
    short8 a1 = *(const short8*)(Ag + (size_t)64 * KK + kb);
    short8 b0 = *(const short8*)(Bg + kb);
    short8 b1 = *(const short8*)(Bg + (size_t)64 * KK + kb);
    __syncthreads();
    *(short8*)&As[sr * 32 + sc] = a0;
    *(short8*)&As[(64 + sr) * 32 + sc] = a1;
    *(short8*)&Bs[sr * 32 + sc] = b0;
    *(short8*)&Bs[(64 + sr) * 32 + sc] = b1;
    __syncthreads();
    short8 af[4], bf[4];
#pragma unroll
    for (int i = 0; i < 4; ++i) {
      af[i] = *(const short8*)&As[(wm + i * 16 + fr) * 32 + fq];
      bf[i] = *(const short8*)&Bs[(wn + i * 16 + fr) * 32 + fq];
    }
#pragma unroll
    for (int i = 0; i < 4; ++i)
#pragma unroll
      for (int j = 0; j < 4; ++j)
        acc[i][j] = __builtin_amdgcn_mfma_f32_16x16x32_bf16(af[i], bf[j], acc[i][j], 0, 0, 0);
  }
  // epilogue: C/D layout col=lane&15, row=(lane>>4)*4+reg
#pragma unroll
  for (int i = 0; i < 4; ++i) {
    int mrow = m0 + wm + i * 16 + quad * 4;
#pragma unroll
    for (int j = 0; j < 4; ++j) {
      int ncol = n0 + wn + j * 16 + fr;
      float bv = bias[ncol];
#pragma unroll
      for (int r = 0; r < 4; ++r) {
        float v = acc[i][j][r] + bv;
        size_t idx = (size_t)(mrow + r) * GG + ncol;
        if (XWF32) ((float*)Cv)[idx] = v;
        else       ((short*)Cv)[idx] = f2bf(v);
      }
    }
  }
}

// ---------------- persistent LSTM scan ----------------
// 128 WGs x 256 threads, one WG per 8 H-columns (x 4 gates = 32 z-cols).
// 4 waves = (nt in 0..1) x (k-half in 0..1); per step 32 MFMAs/wave;
// K-half partials reduced via LDS; 256 gate-threads own (b,j), c in register.
template <bool XWF32>
__global__ __launch_bounds__(256) void lstm_scan(const void* __restrict__ xWv,
                                                 const short* __restrict__ wpack,
                                                 short* __restrict__ hbuf,
                                                 float* __restrict__ out,
                                                 unsigned* __restrict__ bar) {
  const int wg = blockIdx.x;
  const int tid = threadIdx.x;
  const int lane = tid & 63;
  const int wv = tid >> 6;
  const int nt = wv & 1, kh = wv >> 1;
  const int abrow = lane & 15;            // batch row within M-tile
  const int koff = (lane >> 4) * 8;       // k elem offset within 32-chunk
  const short* wpbase = wpack + ((size_t)((wg * 2 + nt) * 32 + kh * 16)) * 512 + lane * 8;

  __shared__ float partials[4 * 2 * 64 * 4];  // [wv][mt][lane][reg], 8 KB

  const int gb = tid >> 3, gj = tid & 7;      // gate-thread (b, jj)
  const int jglob = wg * 8 + gj;
  const int gmt = gb >> 4, grow = gb & 15;
  const int gquad = grow >> 2, gr = grow & 3;
  float c_reg = 0.f;

  const float* xwf = (const float*)xWv;
  const short* xwh = (const short*)xWv;

  int cur = 0;
#pragma unroll 1
  for (int t = 0; t < TT; ++t) {
    const short* hb = hbuf + cur * (BB * KK);
    f32x4 acc0 = (f32x4){0.f, 0.f, 0.f, 0.f};
    f32x4 acc1 = (f32x4){0.f, 0.f, 0.f, 0.f};
    const short* wp = wpbase;
    const short* ha0 = hb + (size_t)abrow * KK + kh * 512 + koff;
    const short* ha1 = hb + (size_t)(abrow + 16) * KK + kh * 512 + koff;
#pragma unroll
    for (int s = 0; s < 16; ++s) {
      short8 bfr = *(const short8*)wp;
      short8 a0 = *(const short8*)(ha0 + s * 32);
      short8 a1 = *(const short8*)(ha1 + s * 32);
      wp += 512;
      acc0 = __builtin_amdgcn_mfma_f32_16x16x32_bf16(a0, bfr, acc0, 0, 0, 0);
      acc1 = __builtin_amdgcn_mfma_f32_16x16x32_bf16(a1, bfr, acc1, 0, 0, 0);
    }
    *(f32x4*)&partials[((wv * 2 + 0) * 64 + lane) * 4] = acc0;
    *(f32x4*)&partials[((wv * 2 + 1) * 64 + lane) * 4] = acc1;
    __syncthreads();

    // gates: z[b][cl], cl = gate*8 + jj; wv = kh*2 + nt
    float z[4];
#pragma unroll
    for (int g = 0; g < 4; ++g) {
      int cl = g * 8 + gj;
      int tnt = cl >> 4, cc = cl & 15;
      int l = gquad * 16 + cc;
      float v = partials[((tnt * 2 + gmt) * 64 + l) * 4 + gr] +
                partials[(((2 + tnt) * 2 + gmt) * 64 + l) * 4 + gr];
      size_t xwi = ((size_t)(gb * TT + t)) * GG + (size_t)g * 1024 + jglob;
      v += XWF32 ? xwf[xwi] : bf2f(xwh[xwi]);
      z[g] = v;
    }
    float i_ = sigmoid_f(z[0]);
    float f_ = sigmoid_f(z[1]);
    float g_ = tanh_f(z[2]);
    float o_ = sigmoid_f(z[3]);
    c_reg = f_ * c_reg + i_ * g_;
    float h_ = o_ * tanh_f(c_reg);
    out[((size_t)gb * TT + t) * 1024 + jglob] = h_;
    hbuf[(cur ^ 1) * (BB * KK) + gb * KK + jglob] = f2bf(h_);

    __syncthreads();  // drains vmcnt: all h stores of this WG are in L2
    if (tid == 0) {
      // release: writes back this XCD's L2 so other XCDs see our h slice
      __hip_atomic_fetch_add(bar, 1u, __ATOMIC_RELEASE, __HIP_MEMORY_SCOPE_AGENT);
      unsigned tgt = (unsigned)SCAN_WGS * (unsigned)(t + 1);
      while (__hip_atomic_load(bar, __ATOMIC_ACQUIRE, __HIP_MEMORY_SCOPE_AGENT) < tgt)
        __builtin_amdgcn_s_sleep(1);
      // acquire invalidates this CU's L1 + XCD L2 -> fresh h next step
    }
    __syncthreads();
    cur ^= 1;
  }
}

// ---------------- launch ----------------

extern "C" void kernel_launch(void* const* d_in, const int* in_sizes, int n_in,
                              void* d_out, int out_size, void* d_ws, size_t ws_size,
                              hipStream_t stream) {
  const float* x    = (const float*)d_in[0];   // [32,512,1024]
  const float* Wih  = (const float*)d_in[1];   // [4096,1024]
  const float* Whh  = (const float*)d_in[2];   // [4096,1024]
  const float* bias = (const float*)d_in[3];   // [4096]
  float* out = (float*)d_out;

  char* ws = (char*)d_ws;
  // ws layout (bytes)
  const size_t o_xbf   = 0;                         // 33,554,432
  const size_t o_wih   = 33554432;                  //  8,388,608
  const size_t o_wpack = 41943040;                  //  8,388,608
  const size_t o_hbuf  = 50331648;                  //    131,072
  const size_t o_bar   = 50462720;                  //        256
  const size_t o_xw    = 50462976;                  // 256 MB (f32) or 128 MB (bf16)
  const bool xwf32 = ws_size >= (o_xw + (size_t)MM * GG * 4);

  short* xbf    = (short*)(ws + o_xbf);
  short* wihbf  = (short*)(ws + o_wih);
  short* wpack  = (short*)(ws + o_wpack);
  short* hbuf   = (short*)(ws + o_hbuf);
  unsigned* bar = (unsigned*)(ws + o_bar);
  void* xw      = (void*)(ws + o_xw);

  // zero h0 double-buffer + barrier counter (ws is poisoned 0xAA each call)
  zero_ws<<<(32832 + 255) / 256, 256, 0, stream>>>((unsigned*)(ws + o_hbuf), 32832);
  // x -> bf16 (16,777,216 elems)
  cvt_bf16<<<16384, 256, 0, stream>>>(x, xbf, 4194304);
  // W_ih -> bf16 (4,194,304 elems)
  cvt_bf16<<<4096, 256, 0, stream>>>(Wih, wihbf, 1048576);
  // W_hh -> packed MFMA-B fragments
  pack_whh<<<2048, 256, 0, stream>>>(Whh, wpack);

  dim3 g1(GG / 128, MM / 128);  // (32, 128)
  if (xwf32) gemm_xw<true ><<<g1, 256, 0, stream>>>(xbf, wihbf, bias, xw);
  else       gemm_xw<false><<<g1, 256, 0, stream>>>(xbf, wihbf, bias, xw);

  if (xwf32) lstm_scan<true ><<<SCAN_WGS, 256, 0, stream>>>(xw, wpack, hbuf, out, bar);
  else       lstm_scan<false><<<SCAN_WGS, 256, 0, stream>>>(xw, wpack, hbuf, out, bar);
}

// Round 2
// 5967.709 us; speedup vs baseline: 1.0012x; 1.0012x over previous
//
#include <hip/hip_runtime.h>
#include <stdint.h>

// Problem constants: B=32, T=512, I=1024, H=1024, 4H=4096, M=B*T=16384.
#define BB 32
#define TT 512
#define KK 1024
#define GG 4096
#define MM 16384
#define SCAN_WGS 64   // WG owns 16 H-cols (x 4 gates = 64 z-cols); 512 threads

typedef __attribute__((ext_vector_type(8))) short short8;
typedef __attribute__((ext_vector_type(4))) short short4v;
typedef __attribute__((ext_vector_type(4))) float f32x4;

__device__ inline short f2bf(float f) {
  union { float f; unsigned u; } v; v.f = f;
  unsigned r = (v.u + 0x7FFFu + ((v.u >> 16) & 1u)) >> 16;  // RNE
  return (short)(unsigned short)r;
}
__device__ inline float bf2f(short s) {
  union { unsigned u; float f; } v; v.u = ((unsigned)(unsigned short)s) << 16;
  return v.f;
}
__device__ inline float sigmoid_f(float x) { return 1.0f / (1.0f + __expf(-x)); }
__device__ inline float tanh_f(float x)    { return 1.0f - 2.0f / (__expf(2.0f * x) + 1.0f); }

// ---------------- prep kernels ----------------

__global__ void zero_ws(unsigned* __restrict__ p, int n) {
  int i = blockIdx.x * 256 + threadIdx.x;
  if (i < n) p[i] = 0u;
}

// float -> bf16, 4 elements/thread
__global__ void cvt_bf16(const float* __restrict__ in, short* __restrict__ out, int n4) {
  int i = blockIdx.x * 256 + threadIdx.x;
  if (i >= n4) return;
  f32x4 v = *(const f32x4*)(in + (size_t)i * 4);
  short4v o;
  o.x = f2bf(v.x); o.y = f2bf(v.y); o.z = f2bf(v.z); o.w = f2bf(v.w);
  *(short4v*)(out + (size_t)i * 4) = o;
}

// Pack W_hh into per-wave MFMA-B-fragment order for the scan.
// Scan WG `wg` (0..63) owns H-cols wg*16..wg*16+15 for each gate.
// Wave wv = g*2+kh (g=gate/n-tile 0..3, kh=K-half 0..1).
// B-frag (16x16x32): B[n=lane&15][k=(lane>>4)*8+j]
//   row(W_hh) = g*1024 + wg*16 + (lane&15)
//   k(W_hh)   = kh*512 + s*32 + (lane>>4)*8 + j     (s = 0..15)
// wpack[((wg*8+wv)*16+s)*512 + lane*8 + j]
__global__ void pack_whh(const float* __restrict__ Whh, short* __restrict__ wpack) {
  int idx = blockIdx.x * 256 + threadIdx.x;          // < 64*8*16*64 = 524288
  if (idx >= SCAN_WGS * 8 * 16 * 64) return;
  int lane = idx & 63;
  int s    = (idx >> 6) & 15;
  int wv   = (idx >> 10) & 7;
  int wg   = idx >> 13;
  int g    = wv >> 1, kh = wv & 1;
  int row  = g * 1024 + wg * 16 + (lane & 15);
  int k    = kh * 512 + s * 32 + (lane >> 4) * 8;
  const float* src = Whh + (size_t)row * KK + k;
  short8 v;
#pragma unroll
  for (int j = 0; j < 8; ++j) v[j] = f2bf(src[j]);
  *(short8*)(wpack + ((size_t)((wg * 8 + wv) * 16 + s)) * 512 + lane * 8) = v;
}

// ---------------- phase 1: xW = x @ W_ih^T + b ----------------
// A = x bf16 [16384][1024]; B = W_ih bf16 [4096][1024] (row-major = B^T form).
// 128x128 tile, BK=32, 256 threads (4 waves in 2x2), 4x4 MFMA tiles per wave.
template <bool XWF32>
__global__ __launch_bounds__(256) void gemm_xw(const short* __restrict__ A,
                                               const short* __restrict__ Bw,
                                               const float* __restrict__ bias,
                                               void* __restrict__ Cv) {
  __shared__ short As[128 * 32];
  __shared__ short Bs[128 * 32];
  const int tid = threadIdx.x;
  const int m0 = blockIdx.y * 128;
  const int n0 = blockIdx.x * 128;
  const int lane = tid & 63, wv = tid >> 6;
  const int wm = (wv >> 1) * 64, wn = (wv & 1) * 64;
  const int fr = lane & 15;               // fragment row/col
  const int fq = (lane >> 4) * 8;         // k-offset (elements)
  const int quad = lane >> 4;
  f32x4 acc[4][4];
#pragma unroll
  for (int i = 0; i < 4; ++i)
#pragma unroll
    for (int j = 0; j < 4; ++j) acc[i][j] = (f32x4){0.f, 0.f, 0.f, 0.f};

  const int sr = tid >> 2;                // staging row 0..63
  const int sc = (tid & 3) * 8;           // staging elem offset
  const short* Ag = A + (size_t)(m0 + sr) * KK + sc;
  const short* Bg = Bw + (size_t)(n0 + sr) * KK + sc;

  for (int kb = 0; kb < KK; kb += 32) {
    short8 a0 = *(const short8*)(Ag + kb);
    short8 a1 = *(const short8*)(Ag + (size_t)64 * KK + kb);
    short8 b0 = *(const short8*)(Bg + kb);
    short8 b1 = *(const short8*)(Bg + (size_t)64 * KK + kb);
    __syncthreads();
    *(short8*)&As[sr * 32 + sc] = a0;
    *(short8*)&As[(64 + sr) * 32 + sc] = a1;
    *(short8*)&Bs[sr * 32 + sc] = b0;
    *(short8*)&Bs[(64 + sr) * 32 + sc] = b1;
    __syncthreads();
    short8 af[4], bf[4];
#pragma unroll
    for (int i = 0; i < 4; ++i) {
      af[i] = *(const short8*)&As[(wm + i * 16 + fr) * 32 + fq];
      bf[i] = *(const short8*)&Bs[(wn + i * 16 + fr) * 32 + fq];
    }
#pragma unroll
    for (int i = 0; i < 4; ++i)
#pragma unroll
      for (int j = 0; j < 4; ++j)
        acc[i][j] = __builtin_amdgcn_mfma_f32_16x16x32_bf16(af[i], bf[j], acc[i][j], 0, 0, 0);
  }
  // epilogue: C/D layout col=lane&15, row=(lane>>4)*4+reg
#pragma unroll
  for (int i = 0; i < 4; ++i) {
    int mrow = m0 + wm + i * 16 + quad * 4;
#pragma unroll
    for (int j = 0; j < 4; ++j) {
      int ncol = n0 + wn + j * 16 + fr;
      float bv = bias[ncol];
#pragma unroll
      for (int r = 0; r < 4; ++r) {
        float v = acc[i][j][r] + bv;
        size_t idx = (size_t)(mrow + r) * GG + ncol;
        if (XWF32) ((float*)Cv)[idx] = v;
        else       ((short*)Cv)[idx] = f2bf(v);
      }
    }
  }
}

// ---------------- persistent LSTM scan ----------------
// 64 WGs x 512 threads. WG wg owns H-cols wg*16..+15 (x4 gates = 64 z-cols).
// 8 waves: wv = g*2+kh (g = gate = n-tile, kh = K-half). W_hh fragments live
// in registers (16 x short8 per lane, loaded once -> immune to per-step L2 inv).
// Per step/wave: 32 MFMAs; K-halves reduced via LDS; 512 gate-threads own
// (b, j) with c in a register. Distributed per-WG-slot barrier (no contended
// fetch_add); xW(t+1) prefetched at top of step t to overlap MFMA phase.
template <bool XWF32>
__global__ __launch_bounds__(512) void lstm_scan(const void* __restrict__ xWv,
                                                 const short* __restrict__ wpack,
                                                 short* __restrict__ hbuf,
                                                 float* __restrict__ out,
                                                 unsigned* __restrict__ arr) {
  const int wg = blockIdx.x;
  const int tid = threadIdx.x;
  const int lane = tid & 63;
  const int wv = tid >> 6;                // 0..7
  const int kh = wv & 1;
  const int abrow = lane & 15;            // batch row within 16-row M-tile
  const int koff = (lane >> 4) * 8;       // k elem offset within 32-chunk

  // preload W_hh B-fragments into registers: 16 x short8 = 64 VGPRs
  short8 wreg[16];
  {
    const short* wp = wpack + ((size_t)((wg * 8 + wv) * 16)) * 512 + lane * 8;
#pragma unroll
    for (int s = 0; s < 16; ++s) wreg[s] = *(const short8*)(wp + s * 512);
  }

  __shared__ float partials[8 * 2 * 64 * 4];  // [wv][mt][lane][reg], 16 KB

  const int gb = tid >> 4, gj = tid & 15;     // gate-thread: batch, j-within-16
  const int jglob = wg * 16 + gj;
  const int gmt = gb >> 4, grow = gb & 15;
  const int gquad = grow >> 2, gr = grow & 3;
  const int gl = (gquad << 4) | gj;           // C-layout lane for (row=grow, col=gj)
  float c_reg = 0.f;

  const float* xwf = (const float*)xWv;
  const short* xwh = (const short*)xWv;

  // prefetch xW for t=0
  float xwv_[4];
#pragma unroll
  for (int g = 0; g < 4; ++g) {
    size_t xi = ((size_t)gb * TT) * GG + (size_t)g * 1024 + jglob;
    xwv_[g] = XWF32 ? xwf[xi] : bf2f(xwh[xi]);
  }

  int cur = 0;
#pragma unroll 1
  for (int t = 0; t < TT; ++t) {
    // prefetch xW(t+1) now; latency overlaps the MFMA/LDS phase below
    float xwn[4];
    if (t + 1 < TT) {
#pragma unroll
      for (int g = 0; g < 4; ++g) {
        size_t xi = ((size_t)(gb * TT + t + 1)) * GG + (size_t)g * 1024 + jglob;
        xwn[g] = XWF32 ? xwf[xi] : bf2f(xwh[xi]);
      }
    }

    const short* hb = hbuf + cur * (BB * KK);
    f32x4 acc0 = (f32x4){0.f, 0.f, 0.f, 0.f};
    f32x4 acc1 = (f32x4){0.f, 0.f, 0.f, 0.f};
    const short* ha0 = hb + (size_t)abrow * KK + kh * 512 + koff;
    const short* ha1 = ha0 + (size_t)16 * KK;
#pragma unroll
    for (int s = 0; s < 16; ++s) {
      short8 a0 = *(const short8*)(ha0 + s * 32);
      short8 a1 = *(const short8*)(ha1 + s * 32);
      acc0 = __builtin_amdgcn_mfma_f32_16x16x32_bf16(a0, wreg[s], acc0, 0, 0, 0);
      acc1 = __builtin_amdgcn_mfma_f32_16x16x32_bf16(a1, wreg[s], acc1, 0, 0, 0);
    }
    *(f32x4*)&partials[((wv * 2 + 0) * 64 + lane) * 4] = acc0;
    *(f32x4*)&partials[((wv * 2 + 1) * 64 + lane) * 4] = acc1;
    __syncthreads();

    // gate g's cols are exactly n-tile g -> waves g*2+0 (kh=0) and g*2+1 (kh=1)
    float z[4];
#pragma unroll
    for (int g = 0; g < 4; ++g) {
      z[g] = partials[(((g * 2 + 0) * 2 + gmt) * 64 + gl) * 4 + gr] +
             partials[(((g * 2 + 1) * 2 + gmt) * 64 + gl) * 4 + gr] + xwv_[g];
    }
    float i_ = sigmoid_f(z[0]);
    float f_ = sigmoid_f(z[1]);
    float g_ = tanh_f(z[2]);
    float o_ = sigmoid_f(z[3]);
    c_reg = f_ * c_reg + i_ * g_;
    float h_ = o_ * tanh_f(c_reg);
    out[((size_t)gb * TT + t) * 1024 + jglob] = h_;
    hbuf[(cur ^ 1) * (BB * KK) + gb * KK + jglob] = f2bf(h_);

    if (t + 1 < TT) {
      __syncthreads();  // waits vmcnt(0): h stores (and prefetch) complete
      if (tid < 64) {   // wave 0 runs the distributed barrier
        unsigned tgt = (unsigned)(t + 1);
        if (tid == 0)   // release: L2 writeback so other XCDs see our h slice
          __hip_atomic_store(&arr[(size_t)wg * 16], tgt, __ATOMIC_RELEASE,
                             __HIP_MEMORY_SCOPE_AGENT);
        unsigned a = 0;
        while (true) {  // each lane polls one WG slot; done lanes stop loading
          if (a < tgt)
            a = __hip_atomic_load(&arr[(size_t)tid * 16], __ATOMIC_RELAXED,
                                  __HIP_MEMORY_SCOPE_AGENT);
          if (__all(a >= tgt)) break;
          __builtin_amdgcn_s_sleep(1);
        }
        // acquire: invalidate L1 + this XCD's L2 -> fresh h reads next step
        (void)__hip_atomic_load(&arr[(size_t)wg * 16], __ATOMIC_ACQUIRE,
                                __HIP_MEMORY_SCOPE_AGENT);
      }
      __syncthreads();
    }
#pragma unroll
    for (int g = 0; g < 4; ++g) xwv_[g] = xwn[g];
    cur ^= 1;
  }
}

// ---------------- launch ----------------

extern "C" void kernel_launch(void* const* d_in, const int* in_sizes, int n_in,
                              void* d_out, int out_size, void* d_ws, size_t ws_size,
                              hipStream_t stream) {
  const float* x    = (const float*)d_in[0];   // [32,512,1024]
  const float* Wih  = (const float*)d_in[1];   // [4096,1024]
  const float* Whh  = (const float*)d_in[2];   // [4096,1024]
  const float* bias = (const float*)d_in[3];   // [4096]
  float* out = (float*)d_out;

  char* ws = (char*)d_ws;
  // ws layout (bytes)
  const size_t o_xbf   = 0;                         // 33,554,432
  const size_t o_wih   = 33554432;                  //  8,388,608
  const size_t o_wpack = 41943040;                  //  8,388,608
  const size_t o_hbuf  = 50331648;                  //    131,072
  const size_t o_bar   = 50462720;                  //      4,096 (64 x 64B slots)
  const size_t o_xw    = 50466816;                  // 256 MB (f32) or 128 MB (bf16)
  const bool xwf32 = ws_size >= (o_xw + (size_t)MM * GG * 4);

  short* xbf    = (short*)(ws + o_xbf);
  short* wihbf  = (short*)(ws + o_wih);
  short* wpack  = (short*)(ws + o_wpack);
  short* hbuf   = (short*)(ws + o_hbuf);
  unsigned* arr = (unsigned*)(ws + o_bar);
  void* xw      = (void*)(ws + o_xw);

  // zero h0 double-buffer + barrier slots (ws is poisoned 0xAA each call)
  zero_ws<<<(33792 + 255) / 256, 256, 0, stream>>>((unsigned*)(ws + o_hbuf), 33792);
  // x -> bf16 (16,777,216 elems)
  cvt_bf16<<<16384, 256, 0, stream>>>(x, xbf, 4194304);
  // W_ih -> bf16 (4,194,304 elems)
  cvt_bf16<<<4096, 256, 0, stream>>>(Wih, wihbf, 1048576);
  // W_hh -> packed MFMA-B fragments
  pack_whh<<<2048, 256, 0, stream>>>(Whh, wpack);

  dim3 g1(GG / 128, MM / 128);  // (32, 128)
  if (xwf32) gemm_xw<true ><<<g1, 256, 0, stream>>>(xbf, wihbf, bias, xw);
  else       gemm_xw<false><<<g1, 256, 0, stream>>>(xbf, wihbf, bias, xw);

  if (xwf32) lstm_scan<true ><<<SCAN_WGS, 512, 0, stream>>>(xw, wpack, hbuf, out, arr);
  else       lstm_scan<false><<<SCAN_WGS, 512, 0, stream>>>(xw, wpack, hbuf, out, arr);
}

// Round 3
// 2454.777 us; speedup vs baseline: 2.4339x; 2.4311x over previous
//
#include <hip/hip_runtime.h>
#include <stdint.h>

// Problem constants: B=32, T=512, I=1024, H=1024, 4H=4096, M=B*T=16384.
#define BB 32
#define TT 512
#define KK 1024
#define GG 4096
#define MM 16384
#define SCAN_WGS 64   // WG owns 16 H-cols (x 4 gates = 64 z-cols); 512 threads
#define HPAD 1032     // LDS h row stride in shorts (1024 + 8 pad)

typedef __attribute__((ext_vector_type(8))) short short8;
typedef __attribute__((ext_vector_type(4))) short short4v;
typedef __attribute__((ext_vector_type(4))) float f32x4;
typedef unsigned long long u64;

__device__ inline short f2bf(float f) {
  union { float f; unsigned u; } v; v.f = f;
  unsigned r = (v.u + 0x7FFFu + ((v.u >> 16) & 1u)) >> 16;  // RNE
  return (short)(unsigned short)r;
}
__device__ inline float bf2f(short s) {
  union { unsigned u; float f; } v; v.u = ((unsigned)(unsigned short)s) << 16;
  return v.f;
}
__device__ inline float sigmoid_f(float x) { return 1.0f / (1.0f + __expf(-x)); }
__device__ inline float tanh_f(float x)    { return 1.0f - 2.0f / (__expf(2.0f * x) + 1.0f); }

// ---------------- prep kernels ----------------

__global__ void zero_ws(unsigned* __restrict__ p, int n) {
  int i = blockIdx.x * 256 + threadIdx.x;
  if (i < n) p[i] = 0u;
}

// float -> bf16, 4 elements/thread
__global__ void cvt_bf16(const float* __restrict__ in, short* __restrict__ out, int n4) {
  int i = blockIdx.x * 256 + threadIdx.x;
  if (i >= n4) return;
  f32x4 v = *(const f32x4*)(in + (size_t)i * 4);
  short4v o;
  o.x = f2bf(v.x); o.y = f2bf(v.y); o.z = f2bf(v.z); o.w = f2bf(v.w);
  *(short4v*)(out + (size_t)i * 4) = o;
}

// Pack W_hh into per-wave MFMA-B-fragment order for the scan.
// Scan WG `wg` (0..63) owns H-cols wg*16..wg*16+15 for each gate.
// Wave wv = g*2+kh (g=gate/n-tile 0..3, kh=K-half 0..1).
// B-frag (16x16x32): B[n=lane&15][k=(lane>>4)*8+j]
//   row(W_hh) = g*1024 + wg*16 + (lane&15)
//   k(W_hh)   = kh*512 + s*32 + (lane>>4)*8 + j     (s = 0..15)
// wpack[((wg*8+wv)*16+s)*512 + lane*8 + j]
__global__ void pack_whh(const float* __restrict__ Whh, short* __restrict__ wpack) {
  int idx = blockIdx.x * 256 + threadIdx.x;          // < 64*8*16*64 = 524288
  if (idx >= SCAN_WGS * 8 * 16 * 64) return;
  int lane = idx & 63;
  int s    = (idx >> 6) & 15;
  int wv   = (idx >> 10) & 7;
  int wg   = idx >> 13;
  int g    = wv >> 1, kh = wv & 1;
  int row  = g * 1024 + wg * 16 + (lane & 15);
  int k    = kh * 512 + s * 32 + (lane >> 4) * 8;
  const float* src = Whh + (size_t)row * KK + k;
  short8 v;
#pragma unroll
  for (int j = 0; j < 8; ++j) v[j] = f2bf(src[j]);
  *(short8*)(wpack + ((size_t)((wg * 8 + wv) * 16 + s)) * 512 + lane * 8) = v;
}

// ---------------- phase 1: xW = x @ W_ih^T + b ----------------
// A = x bf16 [16384][1024]; B = W_ih bf16 [4096][1024] (row-major = B^T form).
// 128x128 tile, BK=32, 256 threads (4 waves in 2x2), 4x4 MFMA tiles per wave.
template <bool XWF32>
__global__ __launch_bounds__(256) void gemm_xw(const short* __restrict__ A,
                                               const short* __restrict__ Bw,
                                               const float* __restrict__ bias,
                                               void* __restrict__ Cv) {
  __shared__ short As[128 * 32];
  __shared__ short Bs[128 * 32];
  const int tid = threadIdx.x;
  const int m0 = blockIdx.y * 128;
  const int n0 = blockIdx.x * 128;
  const int lane = tid & 63, wv = tid >> 6;
  const int wm = (wv >> 1) * 64, wn = (wv & 1) * 64;
  const int fr = lane & 15;               // fragment row/col
  const int fq = (lane >> 4) * 8;         // k-offset (elements)
  const int quad = lane >> 4;
  f32x4 acc[4][4];
#pragma unroll
  for (int i = 0; i < 4; ++i)
#pragma unroll
    for (int j = 0; j < 4; ++j) acc[i][j] = (f32x4){0.f, 0.f, 0.f, 0.f};

  const int sr = tid >> 2;                // staging row 0..63
  const int sc = (tid & 3) * 8;           // staging elem offset
  const short* Ag = A + (size_t)(m0 + sr) * KK + sc;
  const short* Bg = Bw + (size_t)(n0 + sr) * KK + sc;

  for (int kb = 0; kb < KK; kb += 32) {
    short8 a0 = *(const short8*)(Ag + kb);
    short8 a1 = *(const short8*)(Ag + (size_t)64 * KK + kb);
    short8 b0 = *(const short8*)(Bg + kb);
    short8 b1 = *(const short8*)(Bg + (size_t)64 * KK + kb);
    __syncthreads();
    *(short8*)&As[sr * 32 + sc] = a0;
    *(short8*)&As[(64 + sr) * 32 + sc] = a1;
    *(short8*)&Bs[sr * 32 + sc] = b0;
    *(short8*)&Bs[(64 + sr) * 32 + sc] = b1;
    __syncthreads();
    short8 af[4], bf[4];
#pragma unroll
    for (int i = 0; i < 4; ++i) {
      af[i] = *(const short8*)&As[(wm + i * 16 + fr) * 32 + fq];
      bf[i] = *(const short8*)&Bs[(wn + i * 16 + fr) * 32 + fq];
    }
#pragma unroll
    for (int i = 0; i < 4; ++i)
#pragma unroll
      for (int j = 0; j < 4; ++j)
        acc[i][j] = __builtin_amdgcn_mfma_f32_16x16x32_bf16(af[i], bf[j], acc[i][j], 0, 0, 0);
  }
  // epilogue: C/D layout col=lane&15, row=(lane>>4)*4+reg
#pragma unroll
  for (int i = 0; i < 4; ++i) {
    int mrow = m0 + wm + i * 16 + quad * 4;
#pragma unroll
    for (int j = 0; j < 4; ++j) {
      int ncol = n0 + wn + j * 16 + fr;
      float bv = bias[ncol];
#pragma unroll
      for (int r = 0; r < 4; ++r) {
        float v = acc[i][j][r] + bv;
        size_t idx = (size_t)(mrow + r) * GG + ncol;
        if (XWF32) ((float*)Cv)[idx] = v;
        else       ((short*)Cv)[idx] = f2bf(v);
      }
    }
  }
}

// ---------------- persistent LSTM scan ----------------
// 64 WGs x 512 threads. WG wg owns H-cols wg*16..+15 (x4 gates = 64 z-cols).
// NO release/acquire fences (they emit buffer_wbl2 / buffer_inv -> ~7us/step
// L2 walks). All cross-WG data (h, flags) moves with RELAXED agent-scope
// atomics = plain sc1 (device-scope) loads/stores that bypass the XCD L2 and
// are coherent at the memory-side Infinity Cache. __syncthreads' vmcnt(0)
// drain orders h stores before the flag store. h is staged once per step into
// LDS (padded rows, <=2-way bank aliasing); W_hh fragments live in registers.
template <bool XWF32>
__global__ __launch_bounds__(512) void lstm_scan(const void* __restrict__ xWv,
                                                 const short* __restrict__ wpack,
                                                 short* __restrict__ hbuf,
                                                 float* __restrict__ out,
                                                 unsigned* __restrict__ arr) {
  const int wg = blockIdx.x;
  const int tid = threadIdx.x;
  const int lane = tid & 63;
  const int wv = tid >> 6;                // 0..7
  const int kh = wv & 1;
  const int abrow = lane & 15;            // batch row within 16-row M-tile
  const int quad = lane >> 4;

  // preload W_hh B-fragments into registers: 16 x short8 = 64 VGPRs
  short8 wreg[16];
  {
    const short* wp = wpack + ((size_t)((wg * 8 + wv) * 16)) * 512 + lane * 8;
#pragma unroll
    for (int s = 0; s < 16; ++s) wreg[s] = *(const short8*)(wp + s * 512);
  }

  __shared__ short hstage[32 * HPAD];         // 66 KB, padded rows
  __shared__ float partials[8 * 2 * 64 * 4];  // [wv][mt][lane][reg], 16 KB

  const int gb = tid >> 4, gj = tid & 15;     // gate-thread: batch, j-within-16
  const int jglob = wg * 16 + gj;
  const int gmt = gb >> 4, grow = gb & 15;
  const int gquad = grow >> 2, gr = grow & 3;
  const int gl = (gquad << 4) | gj;           // C-layout lane for (row=grow, col=gj)
  float c_reg = 0.f;

  const float* xwf = (const float*)xWv;
  const short* xwh = (const short*)xWv;

  // LDS base for this lane's A-fragment reads (shorts): row=abrow, k-base
  const int lbase0 = abrow * HPAD + kh * 512 + quad * 8;
  const int lbase1 = (abrow + 16) * HPAD + kh * 512 + quad * 8;

  // prefetch xW for t=0
  float xwv_[4];
#pragma unroll
  for (int g = 0; g < 4; ++g) {
    size_t xi = ((size_t)gb * TT) * GG + (size_t)g * 1024 + jglob;
    xwv_[g] = XWF32 ? xwf[xi] : bf2f(xwh[xi]);
  }

  int cur = 0;
#pragma unroll 1
  for (int t = 0; t < TT; ++t) {
    // ---- stage h(t) from LLC into LDS (sc1 loads, bypass stale L2) ----
    const u64* hb64 = (const u64*)(hbuf + cur * (BB * KK));
    u64 hv[16];
#pragma unroll
    for (int it = 0; it < 16; ++it) {
      int c = it * 512 + tid;               // 8192 u64 chunks
      hv[it] = __hip_atomic_load(&hb64[c], __ATOMIC_RELAXED,
                                 __HIP_MEMORY_SCOPE_AGENT);
    }
    // prefetch xW(t+1); latency overlaps MFMA phase
    float xwn[4];
    if (t + 1 < TT) {
#pragma unroll
      for (int g = 0; g < 4; ++g) {
        size_t xi = ((size_t)(gb * TT + t + 1)) * GG + (size_t)g * 1024 + jglob;
        xwn[g] = XWF32 ? xwf[xi] : bf2f(xwh[xi]);
      }
    }
#pragma unroll
    for (int it = 0; it < 16; ++it) {
      int c = it * 512 + tid;
      int row = c >> 8, col8 = c & 255;     // 256 u64 per h row
      *(u64*)&hstage[row * HPAD + col8 * 4] = hv[it];
    }
    __syncthreads();  // S0: hstage visible

    // ---- MFMA phase: A-frags from LDS, B-frags from registers ----
    f32x4 acc0 = (f32x4){0.f, 0.f, 0.f, 0.f};
    f32x4 acc1 = (f32x4){0.f, 0.f, 0.f, 0.f};
#pragma unroll
    for (int s = 0; s < 16; ++s) {
      short8 a0 = *(const short8*)&hstage[lbase0 + s * 32];
      short8 a1 = *(const short8*)&hstage[lbase1 + s * 32];
      acc0 = __builtin_amdgcn_mfma_f32_16x16x32_bf16(a0, wreg[s], acc0, 0, 0, 0);
      acc1 = __builtin_amdgcn_mfma_f32_16x16x32_bf16(a1, wreg[s], acc1, 0, 0, 0);
    }
    *(f32x4*)&partials[((wv * 2 + 0) * 64 + lane) * 4] = acc0;
    *(f32x4*)&partials[((wv * 2 + 1) * 64 + lane) * 4] = acc1;
    __syncthreads();  // S1: partials visible

    // ---- gates: gate g's cols = n-tile g -> waves g*2+0 / g*2+1 ----
    float z[4];
#pragma unroll
    for (int g = 0; g < 4; ++g) {
      z[g] = partials[(((g * 2 + 0) * 2 + gmt) * 64 + gl) * 4 + gr] +
             partials[(((g * 2 + 1) * 2 + gmt) * 64 + gl) * 4 + gr] + xwv_[g];
    }
    float i_ = sigmoid_f(z[0]);
    float f_ = sigmoid_f(z[1]);
    float g_ = tanh_f(z[2]);
    float o_ = sigmoid_f(z[3]);
    c_reg = f_ * c_reg + i_ * g_;
    float h_ = o_ * tanh_f(c_reg);
    out[((size_t)gb * TT + t) * 1024 + jglob] = h_;  // plain cached store

    // ---- h(t+1) store: pack 2 bf16 via shfl, sc1 dword store ----
    unsigned hb16 = (unsigned)(unsigned short)f2bf(h_);
    unsigned oth = __shfl_xor(hb16, 1, 64);
    if (!(gj & 1)) {
      unsigned packed = hb16 | (oth << 16);
      unsigned* dst = (unsigned*)(hbuf + (cur ^ 1) * (BB * KK) + gb * KK + jglob);
      __hip_atomic_store(dst, packed, __ATOMIC_RELAXED, __HIP_MEMORY_SCOPE_AGENT);
    }

    if (t + 1 < TT) {
      __syncthreads();  // S2: vmcnt(0) drain -> h(t+1) visible at LLC
      if (tid < 64) {   // wave 0 runs the distributed flag barrier
        unsigned tgt = (unsigned)(t + 1);
        if (tid == 0)
          __hip_atomic_store(&arr[(size_t)wg * 16], tgt, __ATOMIC_RELAXED,
                             __HIP_MEMORY_SCOPE_AGENT);
        unsigned a = 0;
        while (true) {  // each lane polls one WG slot (relaxed sc1 loads)
          if (a < tgt)
            a = __hip_atomic_load(&arr[(size_t)tid * 16], __ATOMIC_RELAXED,
                                  __HIP_MEMORY_SCOPE_AGENT);
          if (__all(a >= tgt)) break;
          __builtin_amdgcn_s_sleep(1);
        }
      }
      __syncthreads();  // S3
    }
#pragma unroll
    for (int g = 0; g < 4; ++g) xwv_[g] = xwn[g];
    cur ^= 1;
  }
}

// ---------------- launch ----------------

extern "C" void kernel_launch(void* const* d_in, const int* in_sizes, int n_in,
                              void* d_out, int out_size, void* d_ws, size_t ws_size,
                              hipStream_t stream) {
  const float* x    = (const float*)d_in[0];   // [32,512,1024]
  const float* Wih  = (const float*)d_in[1];   // [4096,1024]
  const float* Whh  = (const float*)d_in[2];   // [4096,1024]
  const float* bias = (const float*)d_in[3];   // [4096]
  float* out = (float*)d_out;

  char* ws = (char*)d_ws;
  // ws layout (bytes)
  const size_t o_xbf   = 0;                         // 33,554,432
  const size_t o_wih   = 33554432;                  //  8,388,608
  const size_t o_wpack = 41943040;                  //  8,388,608
  const size_t o_hbuf  = 50331648;                  //    131,072
  const size_t o_bar   = 50462720;                  //      4,096 (64 x 64B slots)
  const size_t o_xw    = 50466816;                  // 256 MB (f32) or 128 MB (bf16)
  const bool xwf32 = ws_size >= (o_xw + (size_t)MM * GG * 4);

  short* xbf    = (short*)(ws + o_xbf);
  short* wihbf  = (short*)(ws + o_wih);
  short* wpack  = (short*)(ws + o_wpack);
  short* hbuf   = (short*)(ws + o_hbuf);
  unsigned* arr = (unsigned*)(ws + o_bar);
  void* xw      = (void*)(ws + o_xw);

  // zero h0 double-buffer + barrier slots (ws is poisoned 0xAA each call)
  zero_ws<<<(33792 + 255) / 256, 256, 0, stream>>>((unsigned*)(ws + o_hbuf), 33792);
  // x -> bf16 (16,777,216 elems)
  cvt_bf16<<<16384, 256, 0, stream>>>(x, xbf, 4194304);
  // W_ih -> bf16 (4,194,304 elems)
  cvt_bf16<<<4096, 256, 0, stream>>>(Wih, wihbf, 1048576);
  // W_hh -> packed MFMA-B fragments
  pack_whh<<<2048, 256, 0, stream>>>(Whh, wpack);

  dim3 g1(GG / 128, MM / 128);  // (32, 128)
  if (xwf32) gemm_xw<true ><<<g1, 256, 0, stream>>>(xbf, wihbf, bias, xw);
  else       gemm_xw<false><<<g1, 256, 0, stream>>>(xbf, wihbf, bias, xw);

  if (xwf32) lstm_scan<true ><<<SCAN_WGS, 512, 0, stream>>>(xw, wpack, hbuf, out, arr);
  else       lstm_scan<false><<<SCAN_WGS, 512, 0, stream>>>(xw, wpack, hbuf, out, arr);
}